// Round 7
// baseline (270.451 us; speedup 1.0000x reference)
//
#include <hip/hip_runtime.h>
#include <hip/hip_bf16.h>
#include <hip/hip_cooperative_groups.h>

namespace cg = cooperative_groups;

typedef __attribute__((ext_vector_type(8))) short short8;
typedef __attribute__((ext_vector_type(4))) float f32x4;
typedef __attribute__((ext_vector_type(16))) float f32x16;
typedef __attribute__((ext_vector_type(8))) int int8v;

#define D   512
#define NQ  2048
#define NS  4096
#define NB  8
#define BM  128
#define BN  128
#define BK  32

typedef const __attribute__((address_space(1))) unsigned int gas_uint;
typedef __attribute__((address_space(3))) unsigned int las_uint;

// s_waitcnt immediates (gfx9): vmcnt[3:0]|[15:14], expcnt[6:4]=7, lgkmcnt[11:8]=15 = no-wait
#define WAIT_VM12  0x0F7C   // vmcnt(12)
#define WAIT_VM8   0x0F78   // vmcnt(8)
#define WAIT_VM4   0x0F74   // vmcnt(4)
#define WAIT_VM0   0x0F70   // vmcnt(0)
#define WAIT_LGKM0 0xC07F   // lgkmcnt(0), vmcnt no-wait

// round-to-nearest-even fp32 -> bf16 bits (fallback path)
__device__ __forceinline__ short f2bf(float f) {
  unsigned u = __builtin_bit_cast(unsigned, f);
  unsigned r = u + 0x7fffu + ((u >> 16) & 1u);
  return (short)(r >> 16);
}

__device__ __forceinline__ short8 pack8(float4 a, float4 b, float r) {
  short8 o;
  o[0] = f2bf(a.x * r); o[1] = f2bf(a.y * r); o[2] = f2bf(a.z * r); o[3] = f2bf(a.w * r);
  o[4] = f2bf(b.x * r); o[5] = f2bf(b.y * r); o[6] = f2bf(b.z * r); o[7] = f2bf(b.w * r);
  return o;
}

// ============================================================================
// fused17: ONE cooperative kernel = normcvt (XCD-aligned) + grid.sync +
// cosmax15 (best measured, 44.5us) + grid.sync + finalize.
// Rationale (r6 post-mortem): e2e - cosmax == ~117us CONSTANT across all six
// rounds — normcvt8 + finalize + inter-kernel drain/fill bubbles + aux
// dispatches. Fusing deletes 2 launches + 2 full-GPU drain bubbles, and the
// XCD-aligned phase-1 (block id handles batch id&7 = the batch its phase-2
// self reads) keeps each batch's 3MB fp8 output resident in that XCD's 4MB
// L2 — the 24MB intermediate never round-trips HBM on the critical path.
// Register wall (r2/r3/r6): this MFMA body can NOT exceed 2 waves/SIMD;
// (256,2) is the only safe bound. Phase-1 regs are disjoint live ranges.
// ============================================================================
__global__ __launch_bounds__(256, 2) void fused17_kernel(
    const float* __restrict__ q, const float* __restrict__ s,
    unsigned char* __restrict__ qn, unsigned char* __restrict__ sn,
    unsigned int* __restrict__ maxenc, float* __restrict__ out)
{
  __shared__ __align__(16) unsigned char sbuf[65536];   // 4 x 16 KB stage buffers
  __shared__ float maxbuf[64][4];
  __shared__ float part[4];

  const int id   = blockIdx.x;         // 512 blocks, 1-D
  const int b    = id & 7;             // XCD-aligned batch (round-robin id->XCD)
  const int g    = id >> 3;            // 0..63
  const int tid  = threadIdx.x;
  const int wave = tid >> 6;           // 0..3
  const int lane = tid & 63;

  // ================= PHASE 1: normalize + fp8-convert (batch b only) =======
  // rows-in-batch rib = (g*4+wave) + 256k, k=0..23  ->  covers [0,6144) once.
  // rib<2048 -> q row, else s row. Writes land in THIS XCD's L2.
  if (id < 64) maxenc[(id << 8) | tid] = 0;
  #pragma clang loop unroll(disable)
  for (int k = 0; k < 24; ++k) {
    const int rib = (g * 4 + wave) + (k << 8);
    const float4* src; unsigned char* dst;
    if (rib < 2048) {
      src = (const float4*)(q + ((size_t)b * NQ + rib) * D);
      dst = qn + ((size_t)b * NQ + rib) * D;
    } else {
      const int r2 = rib - 2048;
      src = (const float4*)(s + ((size_t)b * NS + r2) * D);
      dst = sn + ((size_t)b * NS + r2) * D;
    }
    float4 va = src[lane * 2];
    float4 vb = src[lane * 2 + 1];
    float ss = va.x*va.x + va.y*va.y + va.z*va.z + va.w*va.w
             + vb.x*vb.x + vb.y*vb.y + vb.z*vb.z + vb.w*vb.w;
    #pragma unroll
    for (int m = 32; m >= 1; m >>= 1) ss += __shfl_xor(ss, m, 64);
    float r = 1.0f / fmaxf(sqrtf(ss), 1e-12f);
    int w0 = __builtin_amdgcn_cvt_pk_fp8_f32(va.x * r, va.y * r, 0, false);
    w0     = __builtin_amdgcn_cvt_pk_fp8_f32(va.z * r, va.w * r, w0, true);
    int w1 = __builtin_amdgcn_cvt_pk_fp8_f32(vb.x * r, vb.y * r, 0, false);
    w1     = __builtin_amdgcn_cvt_pk_fp8_f32(vb.z * r, vb.w * r, w1, true);
    *(int2*)(dst + lane * 8) = make_int2(w0, w1);
  }

  cg::this_grid().sync();              // all fp8 written + maxenc zeroed

  // ================= PHASE 2: cosmax15 body (verbatim, best measured) ======
  {
    const int j   = id >> 3;           // 0..63
    const int mt  = j & 31;            // 64-row q tile
    const int nsp = j >> 5;            // 0..1 : 2048-row s half
    const int l31 = lane & 31, kc = lane >> 5;

    // ---- Q prologue: stage 64x512B into sbuf[16384..49152) ----
    {
      const unsigned char* Qbase = qn + ((size_t)b * NQ + (size_t)mt * 64) * D;
      const int baserow = wave * 2 + (lane >> 5);        // 0..7
      #pragma unroll
      for (int p = 0; p < 8; ++p) {
        int row = p * 8 + baserow;                        // 0..63
        int gsw = (lane & 31) ^ (row & 31);               // 16B-chunk XOR swizzle
        __builtin_amdgcn_global_load_lds(
            (gas_uint*)(Qbase + (size_t)row * D + gsw * 16),
            (las_uint*)(sbuf + 16384 + p * 4096 + wave * 1024), 16, 0, 0);
      }
    }
    __syncthreads();                                      // drains Q DMA

    // ---- S staging setup (per-lane global base) ----
    const int srow8 = lane >> 3;                          // 0..7
    const int sch   = (lane & 7) ^ srow8;
    const unsigned char* gS = sn +
        ((size_t)b * NS + (size_t)nsp * 2048 + wave * 32 + srow8) * D + sch * 16;

    auto issue = [&](size_t goff, int ldsoff) {
      #pragma unroll
      for (int t = 0; t < 4; ++t)
        __builtin_amdgcn_global_load_lds((gas_uint*)(gS + goff + (size_t)t * 4096),
            (las_uint*)(sbuf + ldsoff + wave * 4096 + t * 1024), 16, 0, 0);
    };

    issue(0, 0);                                          // (tile0,kt0) -> buf0

    // ---- A fragments: registers, BOTH strips, full K ----
    int8v a[2][8];
    #pragma unroll
    for (int m = 0; m < 2; ++m) {
      const int arow = m * 32 + l31;
      #pragma unroll
      for (int kk = 0; kk < 8; ++kk) {
        int c0 = (4 * kk + 2 * kc) ^ l31;
        ((int4*)&a[m][kk])[0] = *(const int4*)&sbuf[16384 + arow * 512 + c0 * 16];
        ((int4*)&a[m][kk])[1] = *(const int4*)&sbuf[16384 + arow * 512 + (c0 ^ 1) * 16];
      }
    }
    __builtin_amdgcn_s_waitcnt(WAIT_LGKM0);
    asm volatile("" ::: "memory");
    __builtin_amdgcn_s_barrier();
    asm volatile("" ::: "memory");
    issue(128, 16384);                                    // (tile0,kt1) -> buf1
    issue(256, 32768);                                    // (tile0,kt2) -> buf2
    // outstanding: 12 (bufs 0,1,2). No further barriers until epilogue.

    const int brow = (wave * 32 + l31) * 128;
    const int cb0  = ((kc * 2) ^ (l31 & 7)) * 16;
    const int cb1  = cb0 ^ 64;

    f32x16 acc0, acc1;                                    // strip0, strip1
    float rmax0[16], rmax1[16];
    #pragma unroll
    for (int r = 0; r < 16; ++r) { rmax0[r] = -2.0f; rmax1[r] = -2.0f; }

    auto computeK = [&](int kt, int rdo) {
      const unsigned char* Bb = sbuf + rdo;
      int8v b0, b1;
      ((int4*)&b0)[0] = *(const int4*)&Bb[brow + cb0];
      ((int4*)&b0)[1] = *(const int4*)&Bb[brow + (cb0 ^ 16)];
      ((int4*)&b1)[0] = *(const int4*)&Bb[brow + cb1];
      ((int4*)&b1)[1] = *(const int4*)&Bb[brow + (cb1 ^ 16)];
      __builtin_amdgcn_s_setprio(1);
      acc0 = __builtin_amdgcn_mfma_scale_f32_32x32x64_f8f6f4(
          a[0][kt * 2], b0, acc0, 0, 0, 0, 0x7f7f7f7f, 0, 0x7f7f7f7f);
      acc1 = __builtin_amdgcn_mfma_scale_f32_32x32x64_f8f6f4(
          a[1][kt * 2], b0, acc1, 0, 0, 0, 0x7f7f7f7f, 0, 0x7f7f7f7f);
      acc0 = __builtin_amdgcn_mfma_scale_f32_32x32x64_f8f6f4(
          a[0][kt * 2 + 1], b1, acc0, 0, 0, 0, 0x7f7f7f7f, 0, 0x7f7f7f7f);
      acc1 = __builtin_amdgcn_mfma_scale_f32_32x32x64_f8f6f4(
          a[1][kt * 2 + 1], b1, acc1, 0, 0, 0, 0x7f7f7f7f, 0, 0x7f7f7f7f);
      __builtin_amdgcn_s_setprio(0);
    };

    #define KSTEP(WAITIMM)                       \
      asm volatile("" ::: "memory");             \
      __builtin_amdgcn_s_waitcnt(WAITIMM);       \
      asm volatile("" ::: "memory");

    #pragma clang loop unroll(disable)
    for (int nt2 = 0; nt2 < 16; ++nt2) {
      const size_t ntb = (size_t)nt2 << 16;               // 128 rows * 512 B
      const bool more = (nt2 < 15);

      #pragma unroll
      for (int r = 0; r < 16; ++r) { acc0[r] = 0.f; acc1[r] = 0.f; }

      issue(ntb + 384, 49152);
      KSTEP(WAIT_VM12);
      computeK(0, 0);

      if (more) { issue(ntb + 65536, 0); KSTEP(WAIT_VM12); }
      else      { KSTEP(WAIT_VM8); }
      computeK(1, 16384);

      if (more) { issue(ntb + 65536 + 128, 16384); KSTEP(WAIT_VM12); }
      else      { KSTEP(WAIT_VM4); }
      computeK(2, 32768);

      if (more) { issue(ntb + 65536 + 256, 32768); KSTEP(WAIT_VM12); }
      else      { KSTEP(WAIT_VM0); }
      computeK(3, 49152);

      #pragma unroll
      for (int r = 0; r < 16; ++r) {
        rmax0[r] = fmaxf(rmax0[r], acc0[r]);
        rmax1[r] = fmaxf(rmax1[r], acc1[r]);
      }
    }
    #undef KSTEP

    // ---- epilogue: 32x32 C/D col = lane&31, row = (reg&3)+8*(reg>>2)+4*kc --
    #pragma unroll
    for (int m = 0; m < 2; ++m) {
      #pragma unroll
      for (int r = 0; r < 16; ++r) {
        float v = m ? rmax1[r] : rmax0[r];
        v = fmaxf(v, __shfl_xor(v, 1, 64));
        v = fmaxf(v, __shfl_xor(v, 2, 64));
        v = fmaxf(v, __shfl_xor(v, 4, 64));
        v = fmaxf(v, __shfl_xor(v, 8, 64));
        v = fmaxf(v, __shfl_xor(v, 16, 64));
        if (l31 == 0)
          maxbuf[m * 32 + (r & 3) + 8 * (r >> 2) + 4 * kc][wave] = v;
      }
    }
    __syncthreads();

    if (tid < 64) {
      float v = fmaxf(fmaxf(maxbuf[tid][0], maxbuf[tid][1]),
                      fmaxf(maxbuf[tid][2], maxbuf[tid][3]));
      unsigned e = __builtin_bit_cast(unsigned, v);
      e = ((int)e >= 0) ? (e | 0x80000000u) : ~e;         // monotone float->uint
      atomicMax(&maxenc[(size_t)b * NQ + (size_t)mt * 64 + tid], e);
    }
  }

  cg::this_grid().sync();              // all tile maxima merged

  // ================= PHASE 3: finalize (blocks 0..7) ========================
  if (id < 8) {
    float sum = 0.f;
    for (int i = tid; i < NQ; i += 256) {
      unsigned e = maxenc[(size_t)id * NQ + i];
      unsigned u = (e & 0x80000000u) ? (e & 0x7fffffffu) : ~e;
      float v = __builtin_bit_cast(float, u);
      sum += 1.0f - v;
    }
    #pragma unroll
    for (int m = 32; m >= 1; m >>= 1) sum += __shfl_xor(sum, m, 64);
    if ((tid & 63) == 0) part[tid >> 6] = sum;
    __syncthreads();
    if (tid == 0)
      out[id] = (part[0] + part[1] + part[2] + part[3]) * (1.0f / (float)NQ);
  }
}

// ============ standalone 3-kernel fast path (fallback if coop fails) ========
__global__ void normcvt8_kernel(const float* __restrict__ q, const float* __restrict__ s,
                                unsigned char* __restrict__ qn, unsigned char* __restrict__ sn,
                                unsigned* __restrict__ maxenc) {
  if (blockIdx.x < 64) maxenc[(blockIdx.x << 8) | threadIdx.x] = 0;
  int wave = blockIdx.x * 4 + (threadIdx.x >> 6);
  int lane = threadIdx.x & 63;
  const int NQR = NB * NQ;
  const float4* src; unsigned char* dst;
  if (wave < NQR) { src = (const float4*)(q + (size_t)wave * D); dst = qn + (size_t)wave * D; }
  else {
    size_t w = wave - NQR;
    src = (const float4*)(s + w * D); dst = sn + w * D;
  }
  float4 a = src[lane * 2];
  float4 b = src[lane * 2 + 1];
  float ss = a.x*a.x + a.y*a.y + a.z*a.z + a.w*a.w
           + b.x*b.x + b.y*b.y + b.z*b.z + b.w*b.w;
  #pragma unroll
  for (int m = 32; m >= 1; m >>= 1) ss += __shfl_xor(ss, m, 64);
  float r = 1.0f / fmaxf(sqrtf(ss), 1e-12f);
  int w0 = __builtin_amdgcn_cvt_pk_fp8_f32(a.x * r, a.y * r, 0, false);
  w0     = __builtin_amdgcn_cvt_pk_fp8_f32(a.z * r, a.w * r, w0, true);
  int w1 = __builtin_amdgcn_cvt_pk_fp8_f32(b.x * r, b.y * r, 0, false);
  w1     = __builtin_amdgcn_cvt_pk_fp8_f32(b.z * r, b.w * r, w1, true);
  *(int2*)(dst + lane * 8) = make_int2(w0, w1);
}

__global__ __launch_bounds__(256, 2) void cosmax15_kernel(
    const unsigned char* __restrict__ Qn, const unsigned char* __restrict__ Sn,
    unsigned int* __restrict__ maxenc)
{
  __shared__ __align__(16) unsigned char sbuf[65536];
  __shared__ float maxbuf[64][4];

  const int id  = blockIdx.x;
  const int b   = id & 7;
  const int j   = id >> 3;
  const int mt  = j & 31;
  const int nsp = j >> 5;
  const int tid  = threadIdx.x;
  const int wave = tid >> 6;
  const int lane = tid & 63;
  const int l31 = lane & 31, kc = lane >> 5;

  {
    const unsigned char* Qbase = Qn + ((size_t)b * NQ + (size_t)mt * 64) * D;
    const int baserow = wave * 2 + (lane >> 5);
    #pragma unroll
    for (int p = 0; p < 8; ++p) {
      int row = p * 8 + baserow;
      int g   = (lane & 31) ^ (row & 31);
      __builtin_amdgcn_global_load_lds(
          (gas_uint*)(Qbase + (size_t)row * D + g * 16),
          (las_uint*)(sbuf + 16384 + p * 4096 + wave * 1024), 16, 0, 0);
    }
  }
  __syncthreads();

  const int srow8 = lane >> 3;
  const int sch   = (lane & 7) ^ srow8;
  const unsigned char* gS = Sn +
      ((size_t)b * NS + (size_t)nsp * 2048 + wave * 32 + srow8) * D + sch * 16;

  auto issue = [&](size_t goff, int ldsoff) {
    #pragma unroll
    for (int t = 0; t < 4; ++t)
      __builtin_amdgcn_global_load_lds((gas_uint*)(gS + goff + (size_t)t * 4096),
          (las_uint*)(sbuf + ldsoff + wave * 4096 + t * 1024), 16, 0, 0);
  };

  issue(0, 0);

  int8v a[2][8];
  #pragma unroll
  for (int m = 0; m < 2; ++m) {
    const int arow = m * 32 + l31;
    #pragma unroll
    for (int kk = 0; kk < 8; ++kk) {
      int c0 = (4 * kk + 2 * kc) ^ l31;
      ((int4*)&a[m][kk])[0] = *(const int4*)&sbuf[16384 + arow * 512 + c0 * 16];
      ((int4*)&a[m][kk])[1] = *(const int4*)&sbuf[16384 + arow * 512 + (c0 ^ 1) * 16];
    }
  }
  __builtin_amdgcn_s_waitcnt(WAIT_LGKM0);
  asm volatile("" ::: "memory");
  __builtin_amdgcn_s_barrier();
  asm volatile("" ::: "memory");
  issue(128, 16384);
  issue(256, 32768);

  const int brow = (wave * 32 + l31) * 128;
  const int cb0  = ((kc * 2) ^ (l31 & 7)) * 16;
  const int cb1  = cb0 ^ 64;

  f32x16 acc0, acc1;
  float rmax0[16], rmax1[16];
  #pragma unroll
  for (int r = 0; r < 16; ++r) { rmax0[r] = -2.0f; rmax1[r] = -2.0f; }

  auto computeK = [&](int kt, int rdo) {
    const unsigned char* Bb = sbuf + rdo;
    int8v b0, b1;
    ((int4*)&b0)[0] = *(const int4*)&Bb[brow + cb0];
    ((int4*)&b0)[1] = *(const int4*)&Bb[brow + (cb0 ^ 16)];
    ((int4*)&b1)[0] = *(const int4*)&Bb[brow + cb1];
    ((int4*)&b1)[1] = *(const int4*)&Bb[brow + (cb1 ^ 16)];
    __builtin_amdgcn_s_setprio(1);
    acc0 = __builtin_amdgcn_mfma_scale_f32_32x32x64_f8f6f4(
        a[0][kt * 2], b0, acc0, 0, 0, 0, 0x7f7f7f7f, 0, 0x7f7f7f7f);
    acc1 = __builtin_amdgcn_mfma_scale_f32_32x32x64_f8f6f4(
        a[1][kt * 2], b0, acc1, 0, 0, 0, 0x7f7f7f7f, 0, 0x7f7f7f7f);
    acc0 = __builtin_amdgcn_mfma_scale_f32_32x32x64_f8f6f4(
        a[0][kt * 2 + 1], b1, acc0, 0, 0, 0, 0x7f7f7f7f, 0, 0x7f7f7f7f);
    acc1 = __builtin_amdgcn_mfma_scale_f32_32x32x64_f8f6f4(
        a[1][kt * 2 + 1], b1, acc1, 0, 0, 0, 0x7f7f7f7f, 0, 0x7f7f7f7f);
    __builtin_amdgcn_s_setprio(0);
  };

  #define KSTEP(WAITIMM)                       \
    asm volatile("" ::: "memory");             \
    __builtin_amdgcn_s_waitcnt(WAITIMM);       \
    asm volatile("" ::: "memory");

  #pragma clang loop unroll(disable)
  for (int nt2 = 0; nt2 < 16; ++nt2) {
    const size_t ntb = (size_t)nt2 << 16;
    const bool more = (nt2 < 15);

    #pragma unroll
    for (int r = 0; r < 16; ++r) { acc0[r] = 0.f; acc1[r] = 0.f; }

    issue(ntb + 384, 49152);
    KSTEP(WAIT_VM12);
    computeK(0, 0);

    if (more) { issue(ntb + 65536, 0); KSTEP(WAIT_VM12); }
    else      { KSTEP(WAIT_VM8); }
    computeK(1, 16384);

    if (more) { issue(ntb + 65536 + 128, 16384); KSTEP(WAIT_VM12); }
    else      { KSTEP(WAIT_VM4); }
    computeK(2, 32768);

    if (more) { issue(ntb + 65536 + 256, 32768); KSTEP(WAIT_VM12); }
    else      { KSTEP(WAIT_VM0); }
    computeK(3, 49152);

    #pragma unroll
    for (int r = 0; r < 16; ++r) {
      rmax0[r] = fmaxf(rmax0[r], acc0[r]);
      rmax1[r] = fmaxf(rmax1[r], acc1[r]);
    }
  }
  #undef KSTEP

  #pragma unroll
  for (int m = 0; m < 2; ++m) {
    #pragma unroll
    for (int r = 0; r < 16; ++r) {
      float v = m ? rmax1[r] : rmax0[r];
      v = fmaxf(v, __shfl_xor(v, 1, 64));
      v = fmaxf(v, __shfl_xor(v, 2, 64));
      v = fmaxf(v, __shfl_xor(v, 4, 64));
      v = fmaxf(v, __shfl_xor(v, 8, 64));
      v = fmaxf(v, __shfl_xor(v, 16, 64));
      if (l31 == 0)
        maxbuf[m * 32 + (r & 3) + 8 * (r >> 2) + 4 * kc][wave] = v;
    }
  }
  __syncthreads();

  if (tid < 64) {
    float v = fmaxf(fmaxf(maxbuf[tid][0], maxbuf[tid][1]),
                    fmaxf(maxbuf[tid][2], maxbuf[tid][3]));
    unsigned e = __builtin_bit_cast(unsigned, v);
    e = ((int)e >= 0) ? (e | 0x80000000u) : ~e;
    atomicMax(&maxenc[(size_t)b * NQ + (size_t)mt * 64 + tid], e);
  }
}

__global__ void finalize_kernel(const unsigned* __restrict__ maxenc,
                                float* __restrict__ out) {
  int b = blockIdx.x;
  int tid = threadIdx.x;
  float sum = 0.f;
  for (int i = tid; i < NQ; i += 256) {
    unsigned e = maxenc[(size_t)b * NQ + i];
    unsigned u = (e & 0x80000000u) ? (e & 0x7fffffffu) : ~e;
    float v = __builtin_bit_cast(float, u);
    sum += 1.0f - v;
  }
  #pragma unroll
  for (int m = 32; m >= 1; m >>= 1) sum += __shfl_xor(sum, m, 64);
  __shared__ float part[4];
  if ((tid & 63) == 0) part[tid >> 6] = sum;
  __syncthreads();
  if (tid == 0) out[b] = (part[0] + part[1] + part[2] + part[3]) * (1.0f / (float)NQ);
}

// ====================== FALLBACK PATH (round-1, proven, tiny ws) ============
__global__ void norms_kernel(const float* __restrict__ q, const float* __restrict__ s,
                             float* __restrict__ rq, float* __restrict__ rs) {
  int wave = blockIdx.x * 4 + (threadIdx.x >> 6);
  int lane = threadIdx.x & 63;
  const int NQR = NB * NQ, NSR = NB * NS;
  if (wave >= NQR + NSR) return;
  const float4* r4; float* outp;
  if (wave < NQR) { r4 = (const float4*)(q + (size_t)wave * D); outp = rq + wave; }
  else           { r4 = (const float4*)(s + (size_t)(wave - NQR) * D); outp = rs + (wave - NQR); }
  float4 a = r4[lane];
  float4 b = r4[lane + 64];
  float ss = a.x*a.x + a.y*a.y + a.z*a.z + a.w*a.w
           + b.x*b.x + b.y*b.y + b.z*b.z + b.w*b.w;
  #pragma unroll
  for (int m = 32; m >= 1; m >>= 1) ss += __shfl_xor(ss, m, 64);
  if (lane == 0) *outp = 1.0f / fmaxf(sqrtf(ss), 1e-12f);
}

__global__ __launch_bounds__(256, 3) void cosmax_kernel(
    const float* __restrict__ Q, const float* __restrict__ S,
    const float* __restrict__ rq, const float* __restrict__ rs,
    unsigned int* __restrict__ maxenc)
{
  __shared__ short As[BM * BK];
  __shared__ short Bs[BN * BK];
  __shared__ float maxbuf[BM][2];

  const int b  = blockIdx.z, mt = blockIdx.y, nt = blockIdx.x;
  const float* Qb  = Q + ((size_t)b * NQ + mt * BM) * D;
  const float* Sb  = S + ((size_t)b * NS + nt * BN) * D;
  const float* rqb = rq + (size_t)b * NQ + mt * BM;
  const float* rsb = rs + (size_t)b * NS + nt * BN;

  const int tid  = threadIdx.x;
  const int srow = tid >> 2;
  const int kseg = (tid & 3) * 8;
  const float rq0 = rqb[srow], rq1 = rqb[srow + 64];
  const float rs0 = rsb[srow], rs1 = rsb[srow + 64];
  const int wave = tid >> 6, lane = tid & 63;
  const int wm = (wave & 1) * 64, wn = (wave >> 1) * 64;
  const int lm = lane & 15, lk = (lane >> 4) * 8;

  f32x4 acc[4][4];
  #pragma unroll
  for (int i = 0; i < 4; ++i)
    #pragma unroll
    for (int j = 0; j < 4; ++j) acc[i][j] = (f32x4){0.f, 0.f, 0.f, 0.f};

  const float* qrow0 = Qb + (size_t)srow * D + kseg;
  const float* qrow1 = qrow0 + (size_t)64 * D;
  const float* srow0 = Sb + (size_t)srow * D + kseg;
  const float* srow1 = srow0 + (size_t)64 * D;

  float4 qa, qb2, qc, qd, sa, sb2, sc, sd;
  #define LOADK(k0)                                                    \
    qa  = *(const float4*)(qrow0 + (k0));  qb2 = *(const float4*)(qrow0 + (k0) + 4); \
    qc  = *(const float4*)(qrow1 + (k0));  qd  = *(const float4*)(qrow1 + (k0) + 4); \
    sa  = *(const float4*)(srow0 + (k0));  sb2 = *(const float4*)(srow0 + (k0) + 4); \
    sc  = *(const float4*)(srow1 + (k0));  sd  = *(const float4*)(srow1 + (k0) + 4);
  LOADK(0);
  #pragma unroll 4
  for (int kt = 0; kt < D / BK; ++kt) {
    *(short8*)&As[srow        * BK + kseg] = pack8(qa, qb2, rq0);
    *(short8*)&As[(srow + 64) * BK + kseg] = pack8(qc, qd,  rq1);
    *(short8*)&Bs[srow        * BK + kseg] = pack8(sa, sb2, rs0);
    *(short8*)&Bs[(srow + 64) * BK + kseg] = pack8(sc, sd,  rs1);
    __syncthreads();
    if (kt < D / BK - 1) { LOADK((kt + 1) * BK); }
    short8 af[4], bf[4];
    #pragma unroll
    for (int i = 0; i < 4; ++i) af[i] = *(short8*)&As[(wm + i * 16 + lm) * BK + lk];
    #pragma unroll
    for (int j = 0; j < 4; ++j) bf[j] = *(short8*)&Bs[(wn + j * 16 + lm) * BK + lk];
    #pragma unroll
    for (int i = 0; i < 4; ++i)
      #pragma unroll
      for (int j = 0; j < 4; ++j)
        acc[i][j] = __builtin_amdgcn_mfma_f32_16x16x32_bf16(af[i], bf[j], acc[i][j], 0, 0, 0);
    __syncthreads();
  }
  #undef LOADK

  #pragma unroll
  for (int i = 0; i < 4; ++i) {
    #pragma unroll
    for (int r = 0; r < 4; ++r) {
      float v = fmaxf(fmaxf(acc[i][0][r], acc[i][1][r]),
                      fmaxf(acc[i][2][r], acc[i][3][r]));
      v = fmaxf(v, __shfl_xor(v, 1, 64));
      v = fmaxf(v, __shfl_xor(v, 2, 64));
      v = fmaxf(v, __shfl_xor(v, 4, 64));
      v = fmaxf(v, __shfl_xor(v, 8, 64));
      if ((lane & 15) == 0) {
        int row = wm + i * 16 + (lane >> 4) * 4 + r;
        maxbuf[row][wave >> 1] = v;
      }
    }
  }
  __syncthreads();
  if (tid < BM) {
    float v = fmaxf(maxbuf[tid][0], maxbuf[tid][1]);
    unsigned e = __builtin_bit_cast(unsigned, v);
    e = ((int)e >= 0) ? (e | 0x80000000u) : ~e;
    atomicMax(&maxenc[(size_t)b * NQ + mt * BM + tid], e);
  }
}

// ============================================================================
extern "C" void kernel_launch(void* const* d_in, const int* in_sizes, int n_in,
                              void* d_out, int out_size, void* d_ws, size_t ws_size,
                              hipStream_t stream) {
  const float* q = (const float*)d_in[0];   // [8,2048,512]
  const float* s = (const float*)d_in[1];   // [8,4096,512]
  float* out = (float*)d_out;               // [8]

  unsigned* maxenc = (unsigned*)d_ws;                         // 64 KB
  const size_t QOFF = 65536;
  const size_t SOFF = QOFF + (size_t)NB * NQ * D;             // +8 MiB (fp8)
  const size_t NEED = SOFF + (size_t)NB * NS * D;             // +16 MiB (~25.2 MB total)

  if (ws_size >= NEED) {
    unsigned char* qn = (unsigned char*)d_ws + QOFF;
    unsigned char* sn = (unsigned char*)d_ws + SOFF;

    void* args[] = { (void*)&q, (void*)&s, (void*)&qn, (void*)&sn,
                     (void*)&maxenc, (void*)&out };
    hipError_t err = hipLaunchCooperativeKernel(
        (const void*)fused17_kernel, dim3(512), dim3(256), args, 0, stream);
    if (err != hipSuccess) {
      // fallback: proven 3-kernel pipeline (r5, 159.6 us e2e)
      normcvt8_kernel<<<NB * (NQ + NS) / 4, 256, 0, stream>>>(q, s, qn, sn, maxenc);
      cosmax15_kernel<<<512, 256, 0, stream>>>(qn, sn, maxenc);
      finalize_kernel<<<NB, 256, 0, stream>>>(maxenc, out);
    }
  } else {
    float* rq = (float*)((char*)d_ws + 65536);
    float* rs = (float*)((char*)d_ws + 131072);
    hipMemsetAsync(maxenc, 0, (size_t)NB * NQ * sizeof(unsigned), stream);
    norms_kernel<<<NB * (NQ + NS) / 4, 256, 0, stream>>>(q, s, rq, rs);
    dim3 grid(NS / BN, NQ / BM, NB);
    cosmax_kernel<<<grid, 256, 0, stream>>>(q, s, rq, rs, maxenc);
    finalize_kernel<<<NB, 256, 0, stream>>>(maxenc, out);
  }
}

// Round 8
// 231.378 us; speedup vs baseline: 1.1689x; 1.1689x over previous
//
#include <hip/hip_runtime.h>
#include <hip/hip_bf16.h>

typedef __attribute__((ext_vector_type(8))) short short8;
typedef __attribute__((ext_vector_type(4))) float f32x4;
typedef __attribute__((ext_vector_type(16))) float f32x16;
typedef __attribute__((ext_vector_type(8))) int int8v;

#define D   512
#define NQ  2048
#define NS  4096
#define NB  8
#define BM  128
#define BN  128
#define BK  32

typedef const __attribute__((address_space(1))) unsigned int gas_uint;
typedef __attribute__((address_space(3))) unsigned int las_uint;

// round-to-nearest-even fp32 -> bf16 bits (fallback path)
__device__ __forceinline__ short f2bf(float f) {
  unsigned u = __builtin_bit_cast(unsigned, f);
  unsigned r = u + 0x7fffu + ((u >> 16) & 1u);
  return (short)(r >> 16);
}

__device__ __forceinline__ short8 pack8(float4 a, float4 b, float r) {
  short8 o;
  o[0] = f2bf(a.x * r); o[1] = f2bf(a.y * r); o[2] = f2bf(a.z * r); o[3] = f2bf(a.w * r);
  o[4] = f2bf(b.x * r); o[5] = f2bf(b.y * r); o[6] = f2bf(b.z * r); o[7] = f2bf(b.w * r);
  return o;
}

// ============================ FAST PATH (fp8 MX) ============================
__global__ void normcvt8_kernel(const float* __restrict__ q, const float* __restrict__ s,
                                unsigned char* __restrict__ qn, unsigned char* __restrict__ sn,
                                unsigned* __restrict__ maxenc) {
  if (blockIdx.x < 64) maxenc[(blockIdx.x << 8) | threadIdx.x] = 0;
  int wave = blockIdx.x * 4 + (threadIdx.x >> 6);
  int lane = threadIdx.x & 63;
  const int NQR = NB * NQ;
  const float4* src; unsigned char* dst;
  if (wave < NQR) { src = (const float4*)(q + (size_t)wave * D); dst = qn + (size_t)wave * D; }
  else {
    size_t w = wave - NQR;
    src = (const float4*)(s + w * D); dst = sn + w * D;
  }
  float4 a = src[lane * 2];
  float4 b = src[lane * 2 + 1];
  float ss = a.x*a.x + a.y*a.y + a.z*a.z + a.w*a.w
           + b.x*b.x + b.y*b.y + b.z*b.z + b.w*b.w;
  #pragma unroll
  for (int m = 32; m >= 1; m >>= 1) ss += __shfl_xor(ss, m, 64);
  float r = 1.0f / fmaxf(sqrtf(ss), 1e-12f);
  int w0 = __builtin_amdgcn_cvt_pk_fp8_f32(a.x * r, a.y * r, 0, false);
  w0     = __builtin_amdgcn_cvt_pk_fp8_f32(a.z * r, a.w * r, w0, true);
  int w1 = __builtin_amdgcn_cvt_pk_fp8_f32(b.x * r, b.y * r, 0, false);
  w1     = __builtin_amdgcn_cvt_pk_fp8_f32(b.z * r, b.w * r, w1, true);
  *(int2*)(dst + lane * 8) = make_int2(w0, w1);
}

// ---------------------------------------------------------------------------
// cosmax18: cosmax15 minus the LDS round-trip for B.
// r7 insight: in this geometry (waves = n-quarters, A persistent in regs)
// the S-data is WAVE-PRIVATE — LDS staging for B shared nothing. The path
// global_load_lds -> vmcnt -> ds_read_b128 -> lgkm -> MFMA loaded the same
// bytes the MFMA B-fragment needs (per-lane stride-512 16B gather), so the
// direct path global_load_dwordx4 -> vmcnt -> MFMA is strictly fewer ops:
// deletes LDS write+read traffic, the 2.1M bank conflicts, the lgkm waits,
// and halves the VMEM queue pressure. L2 access pattern is UNCHANGED.
//  - B fragment (verified vs cosmax11/15 correctness): lane (l31,kc) of a
//    32-s-row quarter needs bytes {0,16,64,80}+kc*32 of s-row l31's 128B
//    kt-slice -> one per-lane base + 4 imm-offset dwordx4 loads.
//  - 2 register slots (A=even steps, B=odd): consume s, refill s+2. Flight
//    ~1.5-2 computeK spans >= L2 latency; compiler inserts counted vmcnt.
//  - LDS now 32KB (Q only, recycled never) -> zero barriers after prologue.
//  - regs: a[2][8]=128 + 2x16 b + 32 acc + 32 rmax ~= 235 <= (256,2) budget
//    (r5 compiled at 124 VGPR with same demand minus b-slots).
// ---------------------------------------------------------------------------
__global__ __launch_bounds__(256, 2) void cosmax18_kernel(
    const unsigned char* __restrict__ Qn, const unsigned char* __restrict__ Sn,
    unsigned int* __restrict__ maxenc)
{
  __shared__ __align__(16) unsigned char sbuf[32768];   // Q tile only
  __shared__ float maxbuf[64][4];

  const int id  = blockIdx.x;          // 512 blocks, 1-D
  const int b   = id & 7;              // XCD-aligned batch
  const int j   = id >> 3;             // 0..63
  const int mt  = j & 31;              // 64-row q tile
  const int nsp = j >> 5;              // 0..1 : 2048-row s half
  const int tid  = threadIdx.x;
  const int wave = tid >> 6;           // 0..3 : n-quarter (wave-private stream)
  const int lane = tid & 63;
  const int l31 = lane & 31, kc = lane >> 5;

  // ---------------- Q prologue: stage 64x512B into sbuf[0..32768) -----------
  {
    const unsigned char* Qbase = Qn + ((size_t)b * NQ + (size_t)mt * 64) * D;
    const int baserow = wave * 2 + (lane >> 5);          // 0..7
    #pragma unroll
    for (int p = 0; p < 8; ++p) {
      int row = p * 8 + baserow;                          // 0..63
      int g   = (lane & 31) ^ (row & 31);                 // 16B-chunk XOR swizzle
      __builtin_amdgcn_global_load_lds(
          (gas_uint*)(Qbase + (size_t)row * D + g * 16),
          (las_uint*)(sbuf + p * 4096 + wave * 1024), 16, 0, 0);
    }
  }
  __syncthreads();                                        // drains Q DMA

  // ---------------- A fragments: registers, BOTH strips, full K -------------
  int8v a[2][8];
  #pragma unroll
  for (int m = 0; m < 2; ++m) {
    const int arow = m * 32 + l31;
    #pragma unroll
    for (int kk = 0; kk < 8; ++kk) {
      int c0 = (4 * kk + 2 * kc) ^ l31;
      ((int4*)&a[m][kk])[0] = *(const int4*)&sbuf[arow * 512 + c0 * 16];
      ((int4*)&a[m][kk])[1] = *(const int4*)&sbuf[arow * 512 + (c0 ^ 1) * 16];
    }
  }
  // sbuf is never written again -> no barriers needed until the epilogue.

  // ---------------- B: direct global->reg, wave-private stream --------------
  // step s = tile*4 + kt ; per-lane base covers s-row (quarter base + l31),
  // byte kc*32 of each 128B kt-slice. 4 dwordx4 at +0,+16,+64,+80.
  const unsigned char* gB = Sn +
      ((size_t)b * NS + (size_t)nsp * 2048 + wave * 32 + l31) * D + kc * 32;

  auto LOADB = [&](int8v& b0, int8v& b1, int s) {
    const unsigned char* p = gB + ((size_t)(s >> 2) << 16) + ((s & 3) << 7);
    ((int4*)&b0)[0] = *(const int4*)(p);
    ((int4*)&b0)[1] = *(const int4*)(p + 16);
    ((int4*)&b1)[0] = *(const int4*)(p + 64);
    ((int4*)&b1)[1] = *(const int4*)(p + 80);
  };

  f32x16 acc0, acc1;                                      // strip0, strip1
  float rmax0[16], rmax1[16];
  #pragma unroll
  for (int r = 0; r < 16; ++r) { rmax0[r] = -2.0f; rmax1[r] = -2.0f; }

  int8v bA0, bA1, bB0, bB1;
  LOADB(bA0, bA1, 0);                                     // step 0 -> slot A
  LOADB(bB0, bB1, 1);                                     // step 1 -> slot B

  auto computeK = [&](int kk2, const int8v& b0, const int8v& b1) {
    __builtin_amdgcn_s_setprio(1);
    acc0 = __builtin_amdgcn_mfma_scale_f32_32x32x64_f8f6f4(
        a[0][kk2], b0, acc0, 0, 0, 0, 0x7f7f7f7f, 0, 0x7f7f7f7f);
    acc1 = __builtin_amdgcn_mfma_scale_f32_32x32x64_f8f6f4(
        a[1][kk2], b0, acc1, 0, 0, 0, 0x7f7f7f7f, 0, 0x7f7f7f7f);
    acc0 = __builtin_amdgcn_mfma_scale_f32_32x32x64_f8f6f4(
        a[0][kk2 + 1], b1, acc0, 0, 0, 0, 0x7f7f7f7f, 0, 0x7f7f7f7f);
    acc1 = __builtin_amdgcn_mfma_scale_f32_32x32x64_f8f6f4(
        a[1][kk2 + 1], b1, acc1, 0, 0, 0, 0x7f7f7f7f, 0, 0x7f7f7f7f);
    __builtin_amdgcn_s_setprio(0);
  };

  #pragma clang loop unroll(disable)
  for (int nt2 = 0; nt2 < 16; ++nt2) {
    const int s = nt2 * 4;
    const bool more = (nt2 < 15);

    #pragma unroll
    for (int r = 0; r < 16; ++r) { acc0[r] = 0.f; acc1[r] = 0.f; }

    computeK(0, bA0, bA1); LOADB(bA0, bA1, s + 2);        // consume kt0, fetch kt2
    computeK(2, bB0, bB1); LOADB(bB0, bB1, s + 3);        // consume kt1, fetch kt3
    computeK(4, bA0, bA1); if (more) LOADB(bA0, bA1, s + 4);  // kt2 / next kt0
    computeK(6, bB0, bB1); if (more) LOADB(bB0, bB1, s + 5);  // kt3 / next kt1

    #pragma unroll
    for (int r = 0; r < 16; ++r) {
      rmax0[r] = fmaxf(rmax0[r], acc0[r]);
      rmax1[r] = fmaxf(rmax1[r], acc1[r]);
    }
  }

  // ---------------- epilogue -------------------------------------------------
  // 32x32 C/D: col = lane&31 (s-row in quarter), row = (reg&3)+8*(reg>>2)+4*kc
  #pragma unroll
  for (int m = 0; m < 2; ++m) {
    #pragma unroll
    for (int r = 0; r < 16; ++r) {
      float v = m ? rmax1[r] : rmax0[r];
      v = fmaxf(v, __shfl_xor(v, 1, 64));
      v = fmaxf(v, __shfl_xor(v, 2, 64));
      v = fmaxf(v, __shfl_xor(v, 4, 64));
      v = fmaxf(v, __shfl_xor(v, 8, 64));
      v = fmaxf(v, __shfl_xor(v, 16, 64));
      if (l31 == 0)
        maxbuf[m * 32 + (r & 3) + 8 * (r >> 2) + 4 * kc][wave] = v;
    }
  }
  __syncthreads();

  if (tid < 64) {
    float v = fmaxf(fmaxf(maxbuf[tid][0], maxbuf[tid][1]),
                    fmaxf(maxbuf[tid][2], maxbuf[tid][3]));
    unsigned e = __builtin_bit_cast(unsigned, v);
    e = ((int)e >= 0) ? (e | 0x80000000u) : ~e;           // monotone float->uint
    atomicMax(&maxenc[(size_t)b * NQ + (size_t)mt * 64 + tid], e);
  }
}

__global__ void finalize_kernel(const unsigned* __restrict__ maxenc,
                                float* __restrict__ out) {
  int b = blockIdx.x;
  int tid = threadIdx.x;
  float sum = 0.f;
  for (int i = tid; i < NQ; i += 256) {
    unsigned e = maxenc[(size_t)b * NQ + i];
    unsigned u = (e & 0x80000000u) ? (e & 0x7fffffffu) : ~e;
    float v = __builtin_bit_cast(float, u);
    sum += 1.0f - v;
  }
  #pragma unroll
  for (int m = 32; m >= 1; m >>= 1) sum += __shfl_xor(sum, m, 64);
  __shared__ float part[4];
  if ((tid & 63) == 0) part[tid >> 6] = sum;
  __syncthreads();
  if (tid == 0) out[b] = (part[0] + part[1] + part[2] + part[3]) * (1.0f / (float)NQ);
}

// ====================== FALLBACK PATH (round-1, proven, tiny ws) ============
__global__ void norms_kernel(const float* __restrict__ q, const float* __restrict__ s,
                             float* __restrict__ rq, float* __restrict__ rs) {
  int wave = blockIdx.x * 4 + (threadIdx.x >> 6);
  int lane = threadIdx.x & 63;
  const int NQR = NB * NQ, NSR = NB * NS;
  if (wave >= NQR + NSR) return;
  const float4* r4; float* outp;
  if (wave < NQR) { r4 = (const float4*)(q + (size_t)wave * D); outp = rq + wave; }
  else           { r4 = (const float4*)(s + (size_t)(wave - NQR) * D); outp = rs + (wave - NQR); }
  float4 a = r4[lane];
  float4 b = r4[lane + 64];
  float ss = a.x*a.x + a.y*a.y + a.z*a.z + a.w*a.w
           + b.x*b.x + b.y*b.y + b.z*b.z + b.w*b.w;
  #pragma unroll
  for (int m = 32; m >= 1; m >>= 1) ss += __shfl_xor(ss, m, 64);
  if (lane == 0) *outp = 1.0f / fmaxf(sqrtf(ss), 1e-12f);
}

__global__ __launch_bounds__(256, 3) void cosmax_kernel(
    const float* __restrict__ Q, const float* __restrict__ S,
    const float* __restrict__ rq, const float* __restrict__ rs,
    unsigned int* __restrict__ maxenc)
{
  __shared__ short As[BM * BK];
  __shared__ short Bs[BN * BK];
  __shared__ float maxbuf[BM][2];

  const int b  = blockIdx.z, mt = blockIdx.y, nt = blockIdx.x;
  const float* Qb  = Q + ((size_t)b * NQ + mt * BM) * D;
  const float* Sb  = S + ((size_t)b * NS + nt * BN) * D;
  const float* rqb = rq + (size_t)b * NQ + mt * BM;
  const float* rsb = rs + (size_t)b * NS + nt * BN;

  const int tid  = threadIdx.x;
  const int srow = tid >> 2;
  const int kseg = (tid & 3) * 8;
  const float rq0 = rqb[srow], rq1 = rqb[srow + 64];
  const float rs0 = rsb[srow], rs1 = rsb[srow + 64];
  const int wave = tid >> 6, lane = tid & 63;
  const int wm = (wave & 1) * 64, wn = (wave >> 1) * 64;
  const int lm = lane & 15, lk = (lane >> 4) * 8;

  f32x4 acc[4][4];
  #pragma unroll
  for (int i = 0; i < 4; ++i)
    #pragma unroll
    for (int j = 0; j < 4; ++j) acc[i][j] = (f32x4){0.f, 0.f, 0.f, 0.f};

  const float* qrow0 = Qb + (size_t)srow * D + kseg;
  const float* qrow1 = qrow0 + (size_t)64 * D;
  const float* srow0 = Sb + (size_t)srow * D + kseg;
  const float* srow1 = srow0 + (size_t)64 * D;

  float4 qa, qb2, qc, qd, sa, sb2, sc, sd;
  #define LOADK(k0)                                                    \
    qa  = *(const float4*)(qrow0 + (k0));  qb2 = *(const float4*)(qrow0 + (k0) + 4); \
    qc  = *(const float4*)(qrow1 + (k0));  qd  = *(const float4*)(qrow1 + (k0) + 4); \
    sa  = *(const float4*)(srow0 + (k0));  sb2 = *(const float4*)(srow0 + (k0) + 4); \
    sc  = *(const float4*)(srow1 + (k0));  sd  = *(const float4*)(srow1 + (k0) + 4);
  LOADK(0);
  #pragma unroll 4
  for (int kt = 0; kt < D / BK; ++kt) {
    *(short8*)&As[srow        * BK + kseg] = pack8(qa, qb2, rq0);
    *(short8*)&As[(srow + 64) * BK + kseg] = pack8(qc, qd,  rq1);
    *(short8*)&Bs[srow        * BK + kseg] = pack8(sa, sb2, rs0);
    *(short8*)&Bs[(srow + 64) * BK + kseg] = pack8(sc, sd,  rs1);
    __syncthreads();
    if (kt < D / BK - 1) { LOADK((kt + 1) * BK); }
    short8 af[4], bf[4];
    #pragma unroll
    for (int i = 0; i < 4; ++i) af[i] = *(short8*)&As[(wm + i * 16 + lm) * BK + lk];
    #pragma unroll
    for (int j = 0; j < 4; ++j) bf[j] = *(short8*)&Bs[(wn + j * 16 + lm) * BK + lk];
    #pragma unroll
    for (int i = 0; i < 4; ++i)
      #pragma unroll
      for (int j = 0; j < 4; ++j)
        acc[i][j] = __builtin_amdgcn_mfma_f32_16x16x32_bf16(af[i], bf[j], acc[i][j], 0, 0, 0);
    __syncthreads();
  }
  #undef LOADK

  #pragma unroll
  for (int i = 0; i < 4; ++i) {
    #pragma unroll
    for (int r = 0; r < 4; ++r) {
      float v = fmaxf(fmaxf(acc[i][0][r], acc[i][1][r]),
                      fmaxf(acc[i][2][r], acc[i][3][r]));
      v = fmaxf(v, __shfl_xor(v, 1, 64));
      v = fmaxf(v, __shfl_xor(v, 2, 64));
      v = fmaxf(v, __shfl_xor(v, 4, 64));
      v = fmaxf(v, __shfl_xor(v, 8, 64));
      if ((lane & 15) == 0) {
        int row = wm + i * 16 + (lane >> 4) * 4 + r;
        maxbuf[row][wave >> 1] = v;
      }
    }
  }
  __syncthreads();
  if (tid < BM) {
    float v = fmaxf(maxbuf[tid][0], maxbuf[tid][1]);
    unsigned e = __builtin_bit_cast(unsigned, v);
    e = ((int)e >= 0) ? (e | 0x80000000u) : ~e;
    atomicMax(&maxenc[(size_t)b * NQ + mt * BM + tid], e);
  }
}

// ============================================================================
extern "C" void kernel_launch(void* const* d_in, const int* in_sizes, int n_in,
                              void* d_out, int out_size, void* d_ws, size_t ws_size,
                              hipStream_t stream) {
  const float* q = (const float*)d_in[0];   // [8,2048,512]
  const float* s = (const float*)d_in[1];   // [8,4096,512]
  float* out = (float*)d_out;               // [8]

  unsigned* maxenc = (unsigned*)d_ws;                         // 64 KB
  const size_t QOFF = 65536;
  const size_t SOFF = QOFF + (size_t)NB * NQ * D;             // +8 MiB (fp8)
  const size_t NEED = SOFF + (size_t)NB * NS * D;             // +16 MiB (~25.2 MB total)

  if (ws_size >= NEED) {
    unsigned char* qn = (unsigned char*)d_ws + QOFF;
    unsigned char* sn = (unsigned char*)d_ws + SOFF;
    normcvt8_kernel<<<NB * (NQ + NS) / 4, 256, 0, stream>>>(q, s, qn, sn, maxenc);
    cosmax18_kernel<<<512, 256, 0, stream>>>(qn, sn, maxenc);   // direct-B, no LDS hop
    finalize_kernel<<<NB, 256, 0, stream>>>(maxenc, out);
  } else {
    float* rq = (float*)((char*)d_ws + 65536);
    float* rs = (float*)((char*)d_ws + 131072);
    hipMemsetAsync(maxenc, 0, (size_t)NB * NQ * sizeof(unsigned), stream);
    norms_kernel<<<NB * (NQ + NS) / 4, 256, 0, stream>>>(q, s, rq, rs);
    dim3 grid(NS / BN, NQ / BM, NB);
    cosmax_kernel<<<grid, 256, 0, stream>>>(q, s, rq, rs, maxenc);
    finalize_kernel<<<NB, 256, 0, stream>>>(maxenc, out);
  }
}

// Round 10
// 174.933 us; speedup vs baseline: 1.5460x; 1.3227x over previous
//
#include <hip/hip_runtime.h>
#include <hip/hip_bf16.h>

typedef __attribute__((ext_vector_type(8))) short short8;
typedef __attribute__((ext_vector_type(4))) float f32x4;
typedef __attribute__((ext_vector_type(16))) float f32x16;
typedef __attribute__((ext_vector_type(8))) int int8v;

#define D   512
#define NQ  2048
#define NS  4096
#define NB  8
#define BM  128
#define BN  128
#define BK  32

typedef const __attribute__((address_space(1))) unsigned int gas_uint;
typedef __attribute__((address_space(3))) unsigned int las_uint;

// s_waitcnt immediates (gfx9): vmcnt[3:0]|[15:14], expcnt[6:4]=7, lgkmcnt[11:8]=15 = no-wait
#define WAIT_VM8   0x0F78   // vmcnt(8)
#define WAIT_VM4   0x0F74   // vmcnt(4)
#define WAIT_VM0   0x0F70   // vmcnt(0)
#define WAIT_LGKM0 0xC07F   // lgkmcnt(0), vmcnt no-wait

// round-to-nearest-even fp32 -> bf16 bits (fallback path)
__device__ __forceinline__ short f2bf(float f) {
  unsigned u = __builtin_bit_cast(unsigned, f);
  unsigned r = u + 0x7fffu + ((u >> 16) & 1u);
  return (short)(r >> 16);
}

__device__ __forceinline__ short8 pack8(float4 a, float4 b, float r) {
  short8 o;
  o[0] = f2bf(a.x * r); o[1] = f2bf(a.y * r); o[2] = f2bf(a.z * r); o[3] = f2bf(a.w * r);
  o[4] = f2bf(b.x * r); o[5] = f2bf(b.y * r); o[6] = f2bf(b.z * r); o[7] = f2bf(b.w * r);
  return o;
}

// ============================ FAST PATH (fp8 MX) ============================
__global__ void normcvt8_kernel(const float* __restrict__ q, const float* __restrict__ s,
                                unsigned char* __restrict__ qn, unsigned char* __restrict__ sn,
                                unsigned* __restrict__ maxenc) {
  if (blockIdx.x < 64) maxenc[(blockIdx.x << 8) | threadIdx.x] = 0;
  int wave = blockIdx.x * 4 + (threadIdx.x >> 6);
  int lane = threadIdx.x & 63;
  const int NQR = NB * NQ;
  const float4* src; unsigned char* dst;
  if (wave < NQR) { src = (const float4*)(q + (size_t)wave * D); dst = qn + (size_t)wave * D; }
  else {
    size_t w = wave - NQR;
    src = (const float4*)(s + w * D); dst = sn + w * D;
  }
  float4 a = src[lane * 2];
  float4 b = src[lane * 2 + 1];
  float ss = a.x*a.x + a.y*a.y + a.z*a.z + a.w*a.w
           + b.x*b.x + b.y*b.y + b.z*b.z + b.w*b.w;
  #pragma unroll
  for (int m = 32; m >= 1; m >>= 1) ss += __shfl_xor(ss, m, 64);
  float r = 1.0f / fmaxf(sqrtf(ss), 1e-12f);
  int w0 = __builtin_amdgcn_cvt_pk_fp8_f32(a.x * r, a.y * r, 0, false);
  w0     = __builtin_amdgcn_cvt_pk_fp8_f32(a.z * r, a.w * r, w0, true);
  int w1 = __builtin_amdgcn_cvt_pk_fp8_f32(b.x * r, b.y * r, 0, false);
  w1     = __builtin_amdgcn_cvt_pk_fp8_f32(b.z * r, b.w * r, w1, true);
  *(int2*)(dst + lane * 8) = make_int2(w0, w1);
}

// ---------------------------------------------------------------------------
// cosmax19 = cosmax15 (best measured, 44.5us) + register-level frag pipeline.
// r8 lesson: any variant that adds ADDRESSING state spills (4 spills in 7
// tries; allocator splits at 128 and scratch-streams). This change adds only
// ONE extra frag pair (+16 VGPR, same brow/cb0/cb1 bases, no new addresses).
// Mechanism: cosmax15's computeK issues 4 ds_read_b128 and immediately feeds
// the MFMAs -> every step pays ~120cy LDS latency + lgkm drain serially.
// Now step s loads the frags for step s+1 (vmcnt tightened 12->8 so group
// s+1's DMA is confirmed) and MFMAs the frags loaded at s-1: the lgkm wait
// for a frag lands one full step (~275+ cyc of MFMA) after its ds_read.
// Compiler tracks the frag->MFMA dependency and places the lgkm wait itself
// (no inline-asm lgkm -> rule-18 hazard avoided). DMA-overwrite hazard has
// MORE slack than cosmax15 (read at s, overwriting issue at s+2, data
// returns ~a full step later still).
// vmcnt ledger (4-load groups, 3 in flight): steady wait vm(8) = oldest 2
// groups landed; tail t=15: vm(4), vm(0); prologue: vm(8) after g0,g1,g2.
// ---------------------------------------------------------------------------
__global__ __launch_bounds__(256, 2) void cosmax19_kernel(
    const unsigned char* __restrict__ Qn, const unsigned char* __restrict__ Sn,
    unsigned int* __restrict__ maxenc)
{
  __shared__ __align__(16) unsigned char sbuf[65536];   // 4 x 16 KB stage buffers
  __shared__ float maxbuf[64][4];

  const int id  = blockIdx.x;          // 512 blocks, 1-D
  const int b   = id & 7;              // XCD-aligned batch
  const int j   = id >> 3;             // 0..63
  const int mt  = j & 31;              // 64-row q tile
  const int nsp = j >> 5;              // 0..1 : 2048-row s half
  const int tid  = threadIdx.x;
  const int wave = tid >> 6;           // 0..3 : n-quarter (wave-private stream)
  const int lane = tid & 63;
  const int l31 = lane & 31, kc = lane >> 5;

  // ---------------- Q prologue: stage 64x512B into sbuf[16384..49152) -------
  {
    const unsigned char* Qbase = Qn + ((size_t)b * NQ + (size_t)mt * 64) * D;
    const int baserow = wave * 2 + (lane >> 5);          // 0..7
    #pragma unroll
    for (int p = 0; p < 8; ++p) {
      int row = p * 8 + baserow;                          // 0..63
      int g   = (lane & 31) ^ (row & 31);                 // 16B-chunk XOR swizzle
      __builtin_amdgcn_global_load_lds(
          (gas_uint*)(Qbase + (size_t)row * D + g * 16),
          (las_uint*)(sbuf + 16384 + p * 4096 + wave * 1024), 16, 0, 0);
    }
  }
  __syncthreads();                                        // drains Q DMA

  // ---------------- S staging setup (per-lane global base) ------------------
  const int srow8 = lane >> 3;                            // 0..7
  const int sch   = (lane & 7) ^ srow8;
  const unsigned char* gS = Sn +
      ((size_t)b * NS + (size_t)nsp * 2048 + wave * 32 + srow8) * D + sch * 16;

  auto issue = [&](size_t goff, int ldsoff) {
    #pragma unroll
    for (int t = 0; t < 4; ++t)
      __builtin_amdgcn_global_load_lds((gas_uint*)(gS + goff + (size_t)t * 4096),
          (las_uint*)(sbuf + ldsoff + wave * 4096 + t * 1024), 16, 0, 0);
  };

  issue(0, 0);                                            // g0 -> buf0

  // ---------------- A fragments: registers, BOTH strips, full K -------------
  int8v a[2][8];
  #pragma unroll
  for (int m = 0; m < 2; ++m) {
    const int arow = m * 32 + l31;
    #pragma unroll
    for (int kk = 0; kk < 8; ++kk) {
      int c0 = (4 * kk + 2 * kc) ^ l31;
      ((int4*)&a[m][kk])[0] = *(const int4*)&sbuf[16384 + arow * 512 + c0 * 16];
      ((int4*)&a[m][kk])[1] = *(const int4*)&sbuf[16384 + arow * 512 + (c0 ^ 1) * 16];
    }
  }
  // all waves must finish reading Q before stage DMA overwrites buf1/buf2
  __builtin_amdgcn_s_waitcnt(WAIT_LGKM0);
  asm volatile("" ::: "memory");
  __builtin_amdgcn_s_barrier();
  asm volatile("" ::: "memory");
  issue(128, 16384);                                      // g1 -> buf1
  issue(256, 32768);                                      // g2 -> buf2
  // outstanding: 12 (g0,g1,g2).

  const int brow = (wave * 32 + l31) * 128;
  const int cb0  = ((kc * 2) ^ (l31 & 7)) * 16;
  const int cb1  = cb0 ^ 64;

  f32x16 acc0, acc1;                                      // strip0, strip1
  float rmax0[16], rmax1[16];
  #pragma unroll
  for (int r = 0; r < 16; ++r) { rmax0[r] = -2.0f; rmax1[r] = -2.0f; }

  #define KSTEP(WAITIMM)                       \
    asm volatile("" ::: "memory");             \
    __builtin_amdgcn_s_waitcnt(WAITIMM);       \
    asm volatile("" ::: "memory");

  #define LOADFRAG(B0, B1, RDO)                                          \
    { const unsigned char* Bb_ = sbuf + (RDO);                           \
      ((int4*)&B0)[0] = *(const int4*)&Bb_[brow + cb0];                  \
      ((int4*)&B0)[1] = *(const int4*)&Bb_[brow + (cb0 ^ 16)];           \
      ((int4*)&B1)[0] = *(const int4*)&Bb_[brow + cb1];                  \
      ((int4*)&B1)[1] = *(const int4*)&Bb_[brow + (cb1 ^ 16)]; }

  int8v fe0, fe1, fo0, fo1;                               // even/odd frag slots

  auto MFMA4 = [&](int kt, const int8v& b0, const int8v& b1) {
    __builtin_amdgcn_s_setprio(1);
    acc0 = __builtin_amdgcn_mfma_scale_f32_32x32x64_f8f6f4(
        a[0][kt * 2], b0, acc0, 0, 0, 0, 0x7f7f7f7f, 0, 0x7f7f7f7f);
    acc1 = __builtin_amdgcn_mfma_scale_f32_32x32x64_f8f6f4(
        a[1][kt * 2], b0, acc1, 0, 0, 0, 0x7f7f7f7f, 0, 0x7f7f7f7f);
    acc0 = __builtin_amdgcn_mfma_scale_f32_32x32x64_f8f6f4(
        a[0][kt * 2 + 1], b1, acc0, 0, 0, 0, 0x7f7f7f7f, 0, 0x7f7f7f7f);
    acc1 = __builtin_amdgcn_mfma_scale_f32_32x32x64_f8f6f4(
        a[1][kt * 2 + 1], b1, acc1, 0, 0, 0, 0x7f7f7f7f, 0, 0x7f7f7f7f);
    __builtin_amdgcn_s_setprio(0);
  };

  // prologue fill: g0 landed (vm8: 12 outstanding -> 8), frags for step 0
  KSTEP(WAIT_VM8);
  LOADFRAG(fe0, fe1, 0);

  #pragma clang loop unroll(disable)
  for (int nt2 = 0; nt2 < 16; ++nt2) {
    const size_t ntb = (size_t)nt2 << 16;                 // 128 rows * 512 B
    const bool more = (nt2 < 15);

    #pragma unroll
    for (int r = 0; r < 16; ++r) { acc0[r] = 0.f; acc1[r] = 0.f; }

    // kt=0 : issue (tile,kt3)->buf3 ; g(s+1)=buf1 landed ; load odd<-buf1 ; mfma even(buf0)
    issue(ntb + 384, 49152);
    KSTEP(WAIT_VM8);
    LOADFRAG(fo0, fo1, 16384);
    MFMA4(0, fe0, fe1);

    // kt=1 : issue (tile+1,kt0)->buf0 ; buf2 landed ; load even<-buf2 ; mfma odd(buf1)
    if (more) { issue(ntb + 65536, 0); KSTEP(WAIT_VM8); }
    else      { KSTEP(WAIT_VM4); }
    LOADFRAG(fe0, fe1, 32768);
    MFMA4(1, fo0, fo1);

    // kt=2 : issue (tile+1,kt1)->buf1 ; buf3 landed ; load odd<-buf3 ; mfma even(buf2)
    if (more) { issue(ntb + 65536 + 128, 16384); KSTEP(WAIT_VM8); }
    else      { KSTEP(WAIT_VM0); }
    LOADFRAG(fo0, fo1, 49152);
    MFMA4(2, fe0, fe1);

    // kt=3 : issue (tile+1,kt2)->buf2 ; next buf0 landed ; load even<-buf0 ; mfma odd(buf3)
    if (more) { issue(ntb + 65536 + 256, 32768); KSTEP(WAIT_VM8); LOADFRAG(fe0, fe1, 0); }
    MFMA4(3, fo0, fo1);

    #pragma unroll
    for (int r = 0; r < 16; ++r) {
      rmax0[r] = fmaxf(rmax0[r], acc0[r]);
      rmax1[r] = fmaxf(rmax1[r], acc1[r]);
    }
  }
  #undef KSTEP
  #undef LOADFRAG

  // ---------------- epilogue -------------------------------------------------
  // 32x32 C/D: col = lane&31 (s-row in quarter), row = (reg&3)+8*(reg>>2)+4*kc
  #pragma unroll
  for (int m = 0; m < 2; ++m) {
    #pragma unroll
    for (int r = 0; r < 16; ++r) {
      float v = m ? rmax1[r] : rmax0[r];
      v = fmaxf(v, __shfl_xor(v, 1, 64));
      v = fmaxf(v, __shfl_xor(v, 2, 64));
      v = fmaxf(v, __shfl_xor(v, 4, 64));
      v = fmaxf(v, __shfl_xor(v, 8, 64));
      v = fmaxf(v, __shfl_xor(v, 16, 64));
      if (l31 == 0)
        maxbuf[m * 32 + (r & 3) + 8 * (r >> 2) + 4 * kc][wave] = v;
    }
  }
  __syncthreads();

  if (tid < 64) {
    float v = fmaxf(fmaxf(maxbuf[tid][0], maxbuf[tid][1]),
                    fmaxf(maxbuf[tid][2], maxbuf[tid][3]));
    unsigned e = __builtin_bit_cast(unsigned, v);
    e = ((int)e >= 0) ? (e | 0x80000000u) : ~e;           // monotone float->uint
    atomicMax(&maxenc[(size_t)b * NQ + (size_t)mt * 64 + tid], e);
  }
}

__global__ void finalize_kernel(const unsigned* __restrict__ maxenc,
                                float* __restrict__ out) {
  int b = blockIdx.x;
  int tid = threadIdx.x;
  float sum = 0.f;
  for (int i = tid; i < NQ; i += 256) {
    unsigned e = maxenc[(size_t)b * NQ + i];
    unsigned u = (e & 0x80000000u) ? (e & 0x7fffffffu) : ~e;
    float v = __builtin_bit_cast(float, u);
    sum += 1.0f - v;
  }
  #pragma unroll
  for (int m = 32; m >= 1; m >>= 1) sum += __shfl_xor(sum, m, 64);
  __shared__ float part[4];
  if ((tid & 63) == 0) part[tid >> 6] = sum;
  __syncthreads();
  if (tid == 0) out[b] = (part[0] + part[1] + part[2] + part[3]) * (1.0f / (float)NQ);
}

// ====================== FALLBACK PATH (round-1, proven, tiny ws) ============
__global__ void norms_kernel(const float* __restrict__ q, const float* __restrict__ s,
                             float* __restrict__ rq, float* __restrict__ rs) {
  int wave = blockIdx.x * 4 + (threadIdx.x >> 6);
  int lane = threadIdx.x & 63;
  const int NQR = NB * NQ, NSR = NB * NS;
  if (wave >= NQR + NSR) return;
  const float4* r4; float* outp;
  if (wave < NQR) { r4 = (const float4*)(q + (size_t)wave * D); outp = rq + wave; }
  else           { r4 = (const float4*)(s + (size_t)(wave - NQR) * D); outp = rs + (wave - NQR); }
  float4 a = r4[lane];
  float4 b = r4[lane + 64];
  float ss = a.x*a.x + a.y*a.y + a.z*a.z + a.w*a.w
           + b.x*b.x + b.y*b.y + b.z*b.z + b.w*b.w;
  #pragma unroll
  for (int m = 32; m >= 1; m >>= 1) ss += __shfl_xor(ss, m, 64);
  if (lane == 0) *outp = 1.0f / fmaxf(sqrtf(ss), 1e-12f);
}

__global__ __launch_bounds__(256, 3) void cosmax_kernel(
    const float* __restrict__ Q, const float* __restrict__ S,
    const float* __restrict__ rq, const float* __restrict__ rs,
    unsigned int* __restrict__ maxenc)
{
  __shared__ short As[BM * BK];
  __shared__ short Bs[BN * BK];
  __shared__ float maxbuf[BM][2];

  const int b  = blockIdx.z, mt = blockIdx.y, nt = blockIdx.x;
  const float* Qb  = Q + ((size_t)b * NQ + mt * BM) * D;
  const float* Sb  = S + ((size_t)b * NS + nt * BN) * D;
  const float* rqb = rq + (size_t)b * NQ + mt * BM;
  const float* rsb = rs + (size_t)b * NS + nt * BN;

  const int tid  = threadIdx.x;
  const int srow = tid >> 2;
  const int kseg = (tid & 3) * 8;
  const float rq0 = rqb[srow], rq1 = rqb[srow + 64];
  const float rs0 = rsb[srow], rs1 = rsb[srow + 64];
  const int wave = tid >> 6, lane = tid & 63;
  const int wm = (wave & 1) * 64, wn = (wave >> 1) * 64;
  const int lm = lane & 15, lk = (lane >> 4) * 8;

  f32x4 acc[4][4];
  #pragma unroll
  for (int i = 0; i < 4; ++i)
    #pragma unroll
    for (int j = 0; j < 4; ++j) acc[i][j] = (f32x4){0.f, 0.f, 0.f, 0.f};

  const float* qrow0 = Qb + (size_t)srow * D + kseg;
  const float* qrow1 = qrow0 + (size_t)64 * D;
  const float* srow0 = Sb + (size_t)srow * D + kseg;
  const float* srow1 = srow0 + (size_t)64 * D;

  float4 qa, qb2, qc, qd, sa, sb2, sc, sd;
  #define LOADK(k0)                                                    \
    qa  = *(const float4*)(qrow0 + (k0));  qb2 = *(const float4*)(qrow0 + (k0) + 4); \
    qc  = *(const float4*)(qrow1 + (k0));  qd  = *(const float4*)(qrow1 + (k0) + 4); \
    sa  = *(const float4*)(srow0 + (k0));  sb2 = *(const float4*)(srow0 + (k0) + 4); \
    sc  = *(const float4*)(srow1 + (k0));  sd  = *(const float4*)(srow1 + (k0) + 4);
  LOADK(0);
  #pragma unroll 4
  for (int kt = 0; kt < D / BK; ++kt) {
    *(short8*)&As[srow        * BK + kseg] = pack8(qa, qb2, rq0);
    *(short8*)&As[(srow + 64) * BK + kseg] = pack8(qc, qd,  rq1);
    *(short8*)&Bs[srow        * BK + kseg] = pack8(sa, sb2, rs0);
    *(short8*)&Bs[(srow + 64) * BK + kseg] = pack8(sc, sd,  rs1);
    __syncthreads();
    if (kt < D / BK - 1) { LOADK((kt + 1) * BK); }
    short8 af[4], bf[4];
    #pragma unroll
    for (int i = 0; i < 4; ++i) af[i] = *(short8*)&As[(wm + i * 16 + lm) * BK + lk];
    #pragma unroll
    for (int j = 0; j < 4; ++j) bf[j] = *(short8*)&Bs[(wn + j * 16 + lm) * BK + lk];
    #pragma unroll
    for (int i = 0; i < 4; ++i)
      #pragma unroll
      for (int j = 0; j < 4; ++j)
        acc[i][j] = __builtin_amdgcn_mfma_f32_16x16x32_bf16(af[i], bf[j], acc[i][j], 0, 0, 0);
    __syncthreads();
  }
  #undef LOADK

  #pragma unroll
  for (int i = 0; i < 4; ++i) {
    #pragma unroll
    for (int r = 0; r < 4; ++r) {
      float v = fmaxf(fmaxf(acc[i][0][r], acc[i][1][r]),
                      fmaxf(acc[i][2][r], acc[i][3][r]));
      v = fmaxf(v, __shfl_xor(v, 1, 64));
      v = fmaxf(v, __shfl_xor(v, 2, 64));
      v = fmaxf(v, __shfl_xor(v, 4, 64));
      v = fmaxf(v, __shfl_xor(v, 8, 64));
      if ((lane & 15) == 0) {
        int row = wm + i * 16 + (lane >> 4) * 4 + r;
        maxbuf[row][wave >> 1] = v;
      }
    }
  }
  __syncthreads();
  if (tid < BM) {
    float v = fmaxf(maxbuf[tid][0], maxbuf[tid][1]);
    unsigned e = __builtin_bit_cast(unsigned, v);
    e = ((int)e >= 0) ? (e | 0x80000000u) : ~e;
    atomicMax(&maxenc[(size_t)b * NQ + mt * BM + tid], e);
  }
}

// ============================================================================
extern "C" void kernel_launch(void* const* d_in, const int* in_sizes, int n_in,
                              void* d_out, int out_size, void* d_ws, size_t ws_size,
                              hipStream_t stream) {
  const float* q = (const float*)d_in[0];   // [8,2048,512]
  const float* s = (const float*)d_in[1];   // [8,4096,512]
  float* out = (float*)d_out;               // [8]

  unsigned* maxenc = (unsigned*)d_ws;                         // 64 KB
  const size_t QOFF = 65536;
  const size_t SOFF = QOFF + (size_t)NB * NQ * D;             // +8 MiB (fp8)
  const size_t NEED = SOFF + (size_t)NB * NS * D;             // +16 MiB (~25.2 MB total)

  if (ws_size >= NEED) {
    unsigned char* qn = (unsigned char*)d_ws + QOFF;
    unsigned char* sn = (unsigned char*)d_ws + SOFF;
    normcvt8_kernel<<<NB * (NQ + NS) / 4, 256, 0, stream>>>(q, s, qn, sn, maxenc);
    cosmax19_kernel<<<512, 256, 0, stream>>>(qn, sn, maxenc);   // frag-pipelined
    finalize_kernel<<<NB, 256, 0, stream>>>(maxenc, out);
  } else {
    float* rq = (float*)((char*)d_ws + 65536);
    float* rs = (float*)((char*)d_ws + 131072);
    hipMemsetAsync(maxenc, 0, (size_t)NB * NQ * sizeof(unsigned), stream);
    norms_kernel<<<NB * (NQ + NS) / 4, 256, 0, stream>>>(q, s, rq, rs);
    dim3 grid(NS / BN, NQ / BM, NB);
    cosmax_kernel<<<grid, 256, 0, stream>>>(q, s, rq, rs, maxenc);
    finalize_kernel<<<NB, 256, 0, stream>>>(maxenc, out);
  }
}

// Round 11
// 160.321 us; speedup vs baseline: 1.6869x; 1.0911x over previous
//
#include <hip/hip_runtime.h>
#include <hip/hip_bf16.h>

typedef __attribute__((ext_vector_type(8))) short short8;
typedef __attribute__((ext_vector_type(4))) float f32x4;
typedef __attribute__((ext_vector_type(16))) float f32x16;
typedef __attribute__((ext_vector_type(8))) int int8v;

#define D   512
#define NQ  2048
#define NS  4096
#define NB  8
#define BM  128
#define BN  128
#define BK  32

typedef const __attribute__((address_space(1))) unsigned int gas_uint;
typedef __attribute__((address_space(3))) unsigned int las_uint;

// s_waitcnt immediates (gfx9): vmcnt[3:0]|[15:14], expcnt[6:4]=7, lgkmcnt[11:8]=15 = no-wait
#define WAIT_VM12  0x0F7C   // vmcnt(12)
#define WAIT_VM8   0x0F78   // vmcnt(8)
#define WAIT_VM4   0x0F74   // vmcnt(4)
#define WAIT_VM0   0x0F70   // vmcnt(0)
#define WAIT_LGKM0 0xC07F   // lgkmcnt(0), vmcnt no-wait

// round-to-nearest-even fp32 -> bf16 bits (fallback path)
__device__ __forceinline__ short f2bf(float f) {
  unsigned u = __builtin_bit_cast(unsigned, f);
  unsigned r = u + 0x7fffu + ((u >> 16) & 1u);
  return (short)(r >> 16);
}

__device__ __forceinline__ short8 pack8(float4 a, float4 b, float r) {
  short8 o;
  o[0] = f2bf(a.x * r); o[1] = f2bf(a.y * r); o[2] = f2bf(a.z * r); o[3] = f2bf(a.w * r);
  o[4] = f2bf(b.x * r); o[5] = f2bf(b.y * r); o[6] = f2bf(b.z * r); o[7] = f2bf(b.w * r);
  return o;
}

// ============================ FAST PATH (fp8 MX) ============================
__global__ void normcvt8_kernel(const float* __restrict__ q, const float* __restrict__ s,
                                unsigned char* __restrict__ qn, unsigned char* __restrict__ sn,
                                unsigned* __restrict__ maxenc) {
  if (blockIdx.x < 64) maxenc[(blockIdx.x << 8) | threadIdx.x] = 0;
  int wave = blockIdx.x * 4 + (threadIdx.x >> 6);
  int lane = threadIdx.x & 63;
  const int NQR = NB * NQ;
  const float4* src; unsigned char* dst;
  if (wave < NQR) { src = (const float4*)(q + (size_t)wave * D); dst = qn + (size_t)wave * D; }
  else {
    size_t w = wave - NQR;
    src = (const float4*)(s + w * D); dst = sn + w * D;
  }
  float4 a = src[lane * 2];
  float4 b = src[lane * 2 + 1];
  float ss = a.x*a.x + a.y*a.y + a.z*a.z + a.w*a.w
           + b.x*b.x + b.y*b.y + b.z*b.z + b.w*b.w;
  #pragma unroll
  for (int m = 32; m >= 1; m >>= 1) ss += __shfl_xor(ss, m, 64);
  float r = 1.0f / fmaxf(sqrtf(ss), 1e-12f);
  int w0 = __builtin_amdgcn_cvt_pk_fp8_f32(a.x * r, a.y * r, 0, false);
  w0     = __builtin_amdgcn_cvt_pk_fp8_f32(a.z * r, a.w * r, w0, true);
  int w1 = __builtin_amdgcn_cvt_pk_fp8_f32(b.x * r, b.y * r, 0, false);
  w1     = __builtin_amdgcn_cvt_pk_fp8_f32(b.z * r, b.w * r, w1, true);
  *(int2*)(dst + lane * 8) = make_int2(w0, w1);
}

// ---------------------------------------------------------------------------
// cosmax15: BARRIER-FREE main loop — the session's best measured kernel
// (44.5us, 124 VGPR, zero spill; r5). Final configuration.
// Post-session constraint summary (r1-r10):
//  - a[2][8] persistent-A (1:1 ds_read:MFMA) occupies ~220/256 VGPR at
//    2 waves/SIMD. EVERY added live register spills: M=128 tiles (r2,r3),
//    3-buffer occupancy (r6), direct-B addressing (r8), frag pipeline
//    (r10) — five spills, all showing the WRITE_SIZE-balloon signature.
//  - sync structure is irrelevant: fine barriers (45.4), pair barriers
//    (46.4), barrier-free+vmcnt+setprio (44.5) are statistically equal.
//    The kernel is latency-bound at 2 waves/SIMD, all pipes ~30%.
//  - e2e = cosmax (44.5) + normcvt/finalize (~25, near BW floor) + ~90us
//    harness-fixed cost (r7 fusion proved launch bubbles are NOT it).
// ---------------------------------------------------------------------------
__global__ __launch_bounds__(256, 2) void cosmax15_kernel(
    const unsigned char* __restrict__ Qn, const unsigned char* __restrict__ Sn,
    unsigned int* __restrict__ maxenc)
{
  __shared__ __align__(16) unsigned char sbuf[65536];   // 4 x 16 KB stage buffers
  __shared__ float maxbuf[64][4];

  const int id  = blockIdx.x;          // 512 blocks, 1-D
  const int b   = id & 7;              // XCD-aligned batch (round-robin id->XCD)
  const int j   = id >> 3;             // 0..63
  const int mt  = j & 31;              // 64-row q tile
  const int nsp = j >> 5;              // 0..1 : 2048-row s half
  const int tid  = threadIdx.x;
  const int wave = tid >> 6;           // 0..3 : n-quarter (wave-private stream)
  const int lane = tid & 63;
  const int l31 = lane & 31, kc = lane >> 5;

  // ---------------- Q prologue: stage 64x512B into sbuf[16384..49152) -------
  {
    const unsigned char* Qbase = Qn + ((size_t)b * NQ + (size_t)mt * 64) * D;
    const int baserow = wave * 2 + (lane >> 5);          // 0..7
    #pragma unroll
    for (int p = 0; p < 8; ++p) {
      int row = p * 8 + baserow;                          // 0..63
      int g   = (lane & 31) ^ (row & 31);                 // 16B-chunk XOR swizzle
      __builtin_amdgcn_global_load_lds(
          (gas_uint*)(Qbase + (size_t)row * D + g * 16),
          (las_uint*)(sbuf + 16384 + p * 4096 + wave * 1024), 16, 0, 0);
    }
  }
  __syncthreads();                                        // drains Q DMA

  // ---------------- S staging setup (per-lane global base) ------------------
  const int srow8 = lane >> 3;                            // 0..7
  const int sch   = (lane & 7) ^ srow8;
  const unsigned char* gS = Sn +
      ((size_t)b * NS + (size_t)nsp * 2048 + wave * 32 + srow8) * D + sch * 16;

  auto issue = [&](size_t goff, int ldsoff) {
    #pragma unroll
    for (int t = 0; t < 4; ++t)
      __builtin_amdgcn_global_load_lds((gas_uint*)(gS + goff + (size_t)t * 4096),
          (las_uint*)(sbuf + ldsoff + wave * 4096 + t * 1024), 16, 0, 0);
  };

  // stage (tile0,kt0) -> buf0 [0,16384): disjoint from Q region; overlaps A reads
  issue(0, 0);

  // ---------------- A fragments: registers, BOTH strips, full K -------------
  int8v a[2][8];
  #pragma unroll
  for (int m = 0; m < 2; ++m) {
    const int arow = m * 32 + l31;
    #pragma unroll
    for (int kk = 0; kk < 8; ++kk) {
      int c0 = (4 * kk + 2 * kc) ^ l31;
      ((int4*)&a[m][kk])[0] = *(const int4*)&sbuf[16384 + arow * 512 + c0 * 16];
      ((int4*)&a[m][kk])[1] = *(const int4*)&sbuf[16384 + arow * 512 + (c0 ^ 1) * 16];
    }
  }
  // all waves must finish reading Q before stage DMA overwrites buf1/buf2
  __builtin_amdgcn_s_waitcnt(WAIT_LGKM0);
  asm volatile("" ::: "memory");
  __builtin_amdgcn_s_barrier();
  asm volatile("" ::: "memory");
  issue(128, 16384);                                      // (tile0,kt1) -> buf1
  issue(256, 32768);                                      // (tile0,kt2) -> buf2
  // outstanding at loop top: 12 (bufs 0,1,2). No further barriers until epilogue.

  // ---------------- accumulators --------------------------------------------
  // this wave's 32 s-rows: global s-row = nsp*2048 + nt2*128 + wave*32 + l31
  const int brow = (wave * 32 + l31) * 128;
  const int cb0  = ((kc * 2) ^ (l31 & 7)) * 16;
  const int cb1  = cb0 ^ 64;

  f32x16 acc0, acc1;                                      // strip0, strip1
  float rmax0[16], rmax1[16];
  #pragma unroll
  for (int r = 0; r < 16; ++r) { rmax0[r] = -2.0f; rmax1[r] = -2.0f; }

  auto computeK = [&](int kt, int rdo) {
    const unsigned char* Bb = sbuf + rdo;
    int8v b0, b1;
    ((int4*)&b0)[0] = *(const int4*)&Bb[brow + cb0];
    ((int4*)&b0)[1] = *(const int4*)&Bb[brow + (cb0 ^ 16)];
    ((int4*)&b1)[0] = *(const int4*)&Bb[brow + cb1];
    ((int4*)&b1)[1] = *(const int4*)&Bb[brow + (cb1 ^ 16)];
    __builtin_amdgcn_s_setprio(1);
    acc0 = __builtin_amdgcn_mfma_scale_f32_32x32x64_f8f6f4(
        a[0][kt * 2], b0, acc0, 0, 0, 0, 0x7f7f7f7f, 0, 0x7f7f7f7f);
    acc1 = __builtin_amdgcn_mfma_scale_f32_32x32x64_f8f6f4(
        a[1][kt * 2], b0, acc1, 0, 0, 0, 0x7f7f7f7f, 0, 0x7f7f7f7f);
    acc0 = __builtin_amdgcn_mfma_scale_f32_32x32x64_f8f6f4(
        a[0][kt * 2 + 1], b1, acc0, 0, 0, 0, 0x7f7f7f7f, 0, 0x7f7f7f7f);
    acc1 = __builtin_amdgcn_mfma_scale_f32_32x32x64_f8f6f4(
        a[1][kt * 2 + 1], b1, acc1, 0, 0, 0, 0x7f7f7f7f, 0, 0x7f7f7f7f);
    __builtin_amdgcn_s_setprio(0);
  };

  // per-wave step: issue(step+3); wait vmcnt(12); ds_read; 4 MFMA
  #define KSTEP(WAITIMM)                       \
    asm volatile("" ::: "memory");             \
    __builtin_amdgcn_s_waitcnt(WAITIMM);       \
    asm volatile("" ::: "memory");

  #pragma clang loop unroll(disable)
  for (int nt2 = 0; nt2 < 16; ++nt2) {
    const size_t ntb = (size_t)nt2 << 16;                 // 128 rows * 512 B
    const bool more = (nt2 < 15);

    #pragma unroll
    for (int r = 0; r < 16; ++r) { acc0[r] = 0.f; acc1[r] = 0.f; }

    // kt=0 : issue (tile,kt3) -> buf3 ; compute buf0
    issue(ntb + 384, 49152);
    KSTEP(WAIT_VM12);
    computeK(0, 0);

    // kt=1 : issue (tile+1,kt0) -> buf0 ; compute buf1
    if (more) { issue(ntb + 65536, 0); KSTEP(WAIT_VM12); }
    else      { KSTEP(WAIT_VM8); }
    computeK(1, 16384);

    // kt=2 : issue (tile+1,kt1) -> buf1 ; compute buf2
    if (more) { issue(ntb + 65536 + 128, 16384); KSTEP(WAIT_VM12); }
    else      { KSTEP(WAIT_VM4); }
    computeK(2, 32768);

    // kt=3 : issue (tile+1,kt2) -> buf2 ; compute buf3
    if (more) { issue(ntb + 65536 + 256, 32768); KSTEP(WAIT_VM12); }
    else      { KSTEP(WAIT_VM0); }
    computeK(3, 49152);

    #pragma unroll
    for (int r = 0; r < 16; ++r) {
      rmax0[r] = fmaxf(rmax0[r], acc0[r]);
      rmax1[r] = fmaxf(rmax1[r], acc1[r]);
    }
  }
  #undef KSTEP

  // ---------------- epilogue -------------------------------------------------
  // 32x32 C/D: col = lane&31 (s-row in quarter), row = (reg&3)+8*(reg>>2)+4*(lane>>5)
  #pragma unroll
  for (int m = 0; m < 2; ++m) {
    #pragma unroll
    for (int r = 0; r < 16; ++r) {
      float v = m ? rmax1[r] : rmax0[r];
      v = fmaxf(v, __shfl_xor(v, 1, 64));
      v = fmaxf(v, __shfl_xor(v, 2, 64));
      v = fmaxf(v, __shfl_xor(v, 4, 64));
      v = fmaxf(v, __shfl_xor(v, 8, 64));
      v = fmaxf(v, __shfl_xor(v, 16, 64));
      if (l31 == 0)
        maxbuf[m * 32 + (r & 3) + 8 * (r >> 2) + 4 * kc][wave] = v;
    }
  }
  __syncthreads();

  if (tid < 64) {
    float v = fmaxf(fmaxf(maxbuf[tid][0], maxbuf[tid][1]),
                    fmaxf(maxbuf[tid][2], maxbuf[tid][3]));
    unsigned e = __builtin_bit_cast(unsigned, v);
    e = ((int)e >= 0) ? (e | 0x80000000u) : ~e;           // monotone float->uint
    atomicMax(&maxenc[(size_t)b * NQ + (size_t)mt * 64 + tid], e);
  }
}

__global__ void finalize_kernel(const unsigned* __restrict__ maxenc,
                                float* __restrict__ out) {
  int b = blockIdx.x;
  int tid = threadIdx.x;
  float sum = 0.f;
  for (int i = tid; i < NQ; i += 256) {
    unsigned e = maxenc[(size_t)b * NQ + i];
    unsigned u = (e & 0x80000000u) ? (e & 0x7fffffffu) : ~e;
    float v = __builtin_bit_cast(float, u);
    sum += 1.0f - v;
  }
  #pragma unroll
  for (int m = 32; m >= 1; m >>= 1) sum += __shfl_xor(sum, m, 64);
  __shared__ float part[4];
  if ((tid & 63) == 0) part[tid >> 6] = sum;
  __syncthreads();
  if (tid == 0) out[b] = (part[0] + part[1] + part[2] + part[3]) * (1.0f / (float)NQ);
}

// ====================== FALLBACK PATH (round-1, proven, tiny ws) ============
__global__ void norms_kernel(const float* __restrict__ q, const float* __restrict__ s,
                             float* __restrict__ rq, float* __restrict__ rs) {
  int wave = blockIdx.x * 4 + (threadIdx.x >> 6);
  int lane = threadIdx.x & 63;
  const int NQR = NB * NQ, NSR = NB * NS;
  if (wave >= NQR + NSR) return;
  const float4* r4; float* outp;
  if (wave < NQR) { r4 = (const float4*)(q + (size_t)wave * D); outp = rq + wave; }
  else           { r4 = (const float4*)(s + (size_t)(wave - NQR) * D); outp = rs + (wave - NQR); }
  float4 a = r4[lane];
  float4 b = r4[lane + 64];
  float ss = a.x*a.x + a.y*a.y + a.z*a.z + a.w*a.w
           + b.x*b.x + b.y*b.y + b.z*b.z + b.w*b.w;
  #pragma unroll
  for (int m = 32; m >= 1; m >>= 1) ss += __shfl_xor(ss, m, 64);
  if (lane == 0) *outp = 1.0f / fmaxf(sqrtf(ss), 1e-12f);
}

__global__ __launch_bounds__(256, 3) void cosmax_kernel(
    const float* __restrict__ Q, const float* __restrict__ S,
    const float* __restrict__ rq, const float* __restrict__ rs,
    unsigned int* __restrict__ maxenc)
{
  __shared__ short As[BM * BK];
  __shared__ short Bs[BN * BK];
  __shared__ float maxbuf[BM][2];

  const int b  = blockIdx.z, mt = blockIdx.y, nt = blockIdx.x;
  const float* Qb  = Q + ((size_t)b * NQ + mt * BM) * D;
  const float* Sb  = S + ((size_t)b * NS + nt * BN) * D;
  const float* rqb = rq + (size_t)b * NQ + mt * BM;
  const float* rsb = rs + (size_t)b * NS + nt * BN;

  const int tid  = threadIdx.x;
  const int srow = tid >> 2;
  const int kseg = (tid & 3) * 8;
  const float rq0 = rqb[srow], rq1 = rqb[srow + 64];
  const float rs0 = rsb[srow], rs1 = rsb[srow + 64];
  const int wave = tid >> 6, lane = tid & 63;
  const int wm = (wave & 1) * 64, wn = (wave >> 1) * 64;
  const int lm = lane & 15, lk = (lane >> 4) * 8;

  f32x4 acc[4][4];
  #pragma unroll
  for (int i = 0; i < 4; ++i)
    #pragma unroll
    for (int j = 0; j < 4; ++j) acc[i][j] = (f32x4){0.f, 0.f, 0.f, 0.f};

  const float* qrow0 = Qb + (size_t)srow * D + kseg;
  const float* qrow1 = qrow0 + (size_t)64 * D;
  const float* srow0 = Sb + (size_t)srow * D + kseg;
  const float* srow1 = srow0 + (size_t)64 * D;

  float4 qa, qb2, qc, qd, sa, sb2, sc, sd;
  #define LOADK(k0)                                                    \
    qa  = *(const float4*)(qrow0 + (k0));  qb2 = *(const float4*)(qrow0 + (k0) + 4); \
    qc  = *(const float4*)(qrow1 + (k0));  qd  = *(const float4*)(qrow1 + (k0) + 4); \
    sa  = *(const float4*)(srow0 + (k0));  sb2 = *(const float4*)(srow0 + (k0) + 4); \
    sc  = *(const float4*)(srow1 + (k0));  sd  = *(const float4*)(srow1 + (k0) + 4);
  LOADK(0);
  #pragma unroll 4
  for (int kt = 0; kt < D / BK; ++kt) {
    *(short8*)&As[srow        * BK + kseg] = pack8(qa, qb2, rq0);
    *(short8*)&As[(srow + 64) * BK + kseg] = pack8(qc, qd,  rq1);
    *(short8*)&Bs[srow        * BK + kseg] = pack8(sa, sb2, rs0);
    *(short8*)&Bs[(srow + 64) * BK + kseg] = pack8(sc, sd,  rs1);
    __syncthreads();
    if (kt < D / BK - 1) { LOADK((kt + 1) * BK); }
    short8 af[4], bf[4];
    #pragma unroll
    for (int i = 0; i < 4; ++i) af[i] = *(short8*)&As[(wm + i * 16 + lm) * BK + lk];
    #pragma unroll
    for (int j = 0; j < 4; ++j) bf[j] = *(short8*)&Bs[(wn + j * 16 + lm) * BK + lk];
    #pragma unroll
    for (int i = 0; i < 4; ++i)
      #pragma unroll
      for (int j = 0; j < 4; ++j)
        acc[i][j] = __builtin_amdgcn_mfma_f32_16x16x32_bf16(af[i], bf[j], acc[i][j], 0, 0, 0);
    __syncthreads();
  }
  #undef LOADK

  #pragma unroll
  for (int i = 0; i < 4; ++i) {
    #pragma unroll
    for (int r = 0; r < 4; ++r) {
      float v = fmaxf(fmaxf(acc[i][0][r], acc[i][1][r]),
                      fmaxf(acc[i][2][r], acc[i][3][r]));
      v = fmaxf(v, __shfl_xor(v, 1, 64));
      v = fmaxf(v, __shfl_xor(v, 2, 64));
      v = fmaxf(v, __shfl_xor(v, 4, 64));
      v = fmaxf(v, __shfl_xor(v, 8, 64));
      if ((lane & 15) == 0) {
        int row = wm + i * 16 + (lane >> 4) * 4 + r;
        maxbuf[row][wave >> 1] = v;
      }
    }
  }
  __syncthreads();
  if (tid < BM) {
    float v = fmaxf(maxbuf[tid][0], maxbuf[tid][1]);
    unsigned e = __builtin_bit_cast(unsigned, v);
    e = ((int)e >= 0) ? (e | 0x80000000u) : ~e;
    atomicMax(&maxenc[(size_t)b * NQ + mt * BM + tid], e);
  }
}

// ============================================================================
extern "C" void kernel_launch(void* const* d_in, const int* in_sizes, int n_in,
                              void* d_out, int out_size, void* d_ws, size_t ws_size,
                              hipStream_t stream) {
  const float* q = (const float*)d_in[0];   // [8,2048,512]
  const float* s = (const float*)d_in[1];   // [8,4096,512]
  float* out = (float*)d_out;               // [8]

  unsigned* maxenc = (unsigned*)d_ws;                         // 64 KB
  const size_t QOFF = 65536;
  const size_t SOFF = QOFF + (size_t)NB * NQ * D;             // +8 MiB (fp8)
  const size_t NEED = SOFF + (size_t)NB * NS * D;             // +16 MiB (~25.2 MB total)

  if (ws_size >= NEED) {
    unsigned char* qn = (unsigned char*)d_ws + QOFF;
    unsigned char* sn = (unsigned char*)d_ws + SOFF;
    normcvt8_kernel<<<NB * (NQ + NS) / 4, 256, 0, stream>>>(q, s, qn, sn, maxenc);
    cosmax15_kernel<<<512, 256, 0, stream>>>(qn, sn, maxenc);   // best measured (r5)
    finalize_kernel<<<NB, 256, 0, stream>>>(maxenc, out);
  } else {
    float* rq = (float*)((char*)d_ws + 65536);
    float* rs = (float*)((char*)d_ws + 131072);
    hipMemsetAsync(maxenc, 0, (size_t)NB * NQ * sizeof(unsigned), stream);
    norms_kernel<<<NB * (NQ + NS) / 4, 256, 0, stream>>>(q, s, rq, rs);
    dim3 grid(NS / BN, NQ / BM, NB);
    cosmax_kernel<<<grid, 256, 0, stream>>>(q, s, rq, rs, maxenc);
    finalize_kernel<<<NB, 256, 0, stream>>>(maxenc, out);
  }
}